// Round 1
// baseline (431.441 us; speedup 1.0000x reference)
//
#include <hip/hip_runtime.h>

// Cosine similarity with 4 diagonal neighbors, summed.
// Input: (2048, 2048, 1, 16) fp32. Output: (2048, 2048) fp32.

#define IMG_H 2048
#define IMG_W 2048
#define IMG_C 16

__device__ __forceinline__ float dot4(float4 a, float4 b) {
    return a.x * b.x + a.y * b.y + a.z * b.z + a.w * b.w;
}

__global__ __launch_bounds__(256) void cos_sim_kernel(
    const float* __restrict__ in, float* __restrict__ out) {
    const int x = blockIdx.x * 32 + threadIdx.x;   // threadIdx.x in [0,32)
    const int y = blockIdx.y * 8  + threadIdx.y;   // threadIdx.y in [0,8)

    // Own pixel vector: 16 floats = 4x float4 (64B, coalesced in aggregate).
    const float4* v = (const float4*)(in + ((size_t)y * IMG_W + x) * IMG_C);
    const float4 a0 = v[0], a1 = v[1], a2 = v[2], a3 = v[3];
    const float na = dot4(a0, a0) + dot4(a1, a1) + dot4(a2, a2) + dot4(a3, a3);

    float sim = 0.0f;

    #pragma unroll
    for (int k = 0; k < 4; ++k) {
        const int dy = (k & 2) ? 1 : -1;
        const int dx = (k & 1) ? 1 : -1;
        const int ny = y + dy;
        const int nx = x + dx;
        const bool valid = ((unsigned)ny < IMG_H) && ((unsigned)nx < IMG_W);
        // Clamp to own pixel so the address is always in-bounds; zero the
        // contribution for invalid neighbors (branch-free, matches reference
        // boundary clipping where edge pixels just get fewer terms).
        const int cy = valid ? ny : y;
        const int cx = valid ? nx : x;
        const float4* u = (const float4*)(in + ((size_t)cy * IMG_W + cx) * IMG_C);
        const float4 b0 = u[0], b1 = u[1], b2 = u[2], b3 = u[3];
        const float dot = dot4(a0, b0) + dot4(a1, b1) + dot4(a2, b2) + dot4(a3, b3);
        const float nb  = dot4(b0, b0) + dot4(b1, b1) + dot4(b2, b2) + dot4(b3, b3);
        // den = max(sqrt(na*nb), 1e-8) == sqrt(max(na*nb, 1e-16))
        const float contrib = dot * rsqrtf(fmaxf(na * nb, 1e-16f));
        sim += valid ? contrib : 0.0f;
    }

    out[(size_t)y * IMG_W + x] = sim;
}

extern "C" void kernel_launch(void* const* d_in, const int* in_sizes, int n_in,
                              void* d_out, int out_size, void* d_ws, size_t ws_size,
                              hipStream_t stream) {
    const float* in = (const float*)d_in[0];
    float* out = (float*)d_out;
    dim3 block(32, 8, 1);
    dim3 grid(IMG_W / 32, IMG_H / 8, 1);
    cos_sim_kernel<<<grid, block, 0, stream>>>(in, out);
}

// Round 2
// 370.287 us; speedup vs baseline: 1.1652x; 1.1652x over previous
//
#include <hip/hip_runtime.h>

// Cosine similarity with 4 diagonal neighbors, summed.
// Input: (2048, 2048, 1, 16) fp32. Output: (2048, 2048) fp32.
//
// R2: LDS-staged tile. R1 was L1-request-bound: stride-64B lane addresses put
// 64 cache lines under every wave load. Now global loads are lane-contiguous
// (16 B/lane), vectors live in LDS at an 80 B stride (16B-aligned for
// ds_read_b128, bank-balanced: start bank (20i)%32 gives every bank exactly
// 8 accesses per wave load = structural minimum), and each pixel's norm is
// computed once into a table instead of 5x.

#define IMG_H 2048
#define IMG_W 2048
#define IMG_C 16

#define TX 32
#define TY 16
#define HX (TX + 2)      // 34
#define HY (TY + 2)      // 18
#define NPIX (HX * HY)   // 612
#define PSTRIDE 20       // floats per pixel slot in LDS (16 data + 4 pad)

__device__ __forceinline__ float dot4(float4 a, float4 b) {
    return a.x * b.x + a.y * b.y + a.z * b.z + a.w * b.w;
}

__global__ __launch_bounds__(256) void cos_sim_kernel(
    const float* __restrict__ in, float* __restrict__ out) {
    __shared__ float tile[NPIX * PSTRIDE];   // 48960 B
    __shared__ float norms[NPIX];            // 2448 B

    const int tid = threadIdx.y * 32 + threadIdx.x;
    const int bx = blockIdx.x * TX;
    const int by = blockIdx.y * TY;

    // ---- Stage (HY x HX) halo tile into LDS; lane-contiguous float4 loads ----
    // linear element i -> pixel p = i>>2, chunk k = i&3; consecutive i are
    // contiguous 16 B in global memory (within a row segment).
    for (int i = tid; i < NPIX * 4; i += 256) {
        const int p = i >> 2;
        const int k = i & 3;
        const int r = p / HX;
        const int c = p - r * HX;
        int gy = by + r - 1;
        int gx = bx + c - 1;
        gy = min(max(gy, 0), IMG_H - 1);
        gx = min(max(gx, 0), IMG_W - 1);
        const float4 v = *(const float4*)(in + ((size_t)gy * IMG_W + gx) * IMG_C + k * 4);
        *(float4*)(tile + p * PSTRIDE + k * 4) = v;
    }
    __syncthreads();

    // ---- Per-pixel squared norms, computed once ----
    for (int p = tid; p < NPIX; p += 256) {
        const float* t = tile + p * PSTRIDE;
        const float4 a0 = *(const float4*)(t + 0);
        const float4 a1 = *(const float4*)(t + 4);
        const float4 a2 = *(const float4*)(t + 8);
        const float4 a3 = *(const float4*)(t + 12);
        norms[p] = dot4(a0, a0) + dot4(a1, a1) + dot4(a2, a2) + dot4(a3, a3);
    }
    __syncthreads();

    // ---- Compute 2 output pixels per thread ----
    #pragma unroll
    for (int rr = 0; rr < 2; ++rr) {
        const int r = threadIdx.y + rr * 8;    // tile row 0..15
        const int c = threadIdx.x;             // tile col 0..31
        const int gy = by + r;
        const int gx = bx + c;
        const int p = (r + 1) * HX + (c + 1);

        const float* t = tile + p * PSTRIDE;
        const float4 a0 = *(const float4*)(t + 0);
        const float4 a1 = *(const float4*)(t + 4);
        const float4 a2 = *(const float4*)(t + 8);
        const float4 a3 = *(const float4*)(t + 12);
        const float na = norms[p];

        float sim = 0.0f;
        #pragma unroll
        for (int q = 0; q < 4; ++q) {
            const int dy = (q & 2) ? 1 : -1;
            const int dx = (q & 1) ? 1 : -1;
            const int np = p + dy * HX + dx;
            const float* u = tile + np * PSTRIDE;
            const float4 b0 = *(const float4*)(u + 0);
            const float4 b1 = *(const float4*)(u + 4);
            const float4 b2 = *(const float4*)(u + 8);
            const float4 b3 = *(const float4*)(u + 12);
            const float dot = dot4(a0, b0) + dot4(a1, b1) + dot4(a2, b2) + dot4(a3, b3);
            const float nb = norms[np];
            const bool valid = ((unsigned)(gy + dy) < IMG_H) && ((unsigned)(gx + dx) < IMG_W);
            const float contrib = dot * rsqrtf(fmaxf(na * nb, 1e-16f));
            sim += valid ? contrib : 0.0f;
        }
        out[(size_t)gy * IMG_W + gx] = sim;
    }
}

extern "C" void kernel_launch(void* const* d_in, const int* in_sizes, int n_in,
                              void* d_out, int out_size, void* d_ws, size_t ws_size,
                              hipStream_t stream) {
    const float* in = (const float*)d_in[0];
    float* out = (float*)d_out;
    dim3 block(32, 8, 1);
    dim3 grid(IMG_W / TX, IMG_H / TY, 1);
    cos_sim_kernel<<<grid, block, 0, stream>>>(in, out);
}

// Round 4
// 353.388 us; speedup vs baseline: 1.2209x; 1.0478x over previous
//
#include <hip/hip_runtime.h>

// Cosine similarity with 4 diagonal neighbors, summed.
// Input: (2048, 2048, 1, 16) fp32. Output: (2048, 2048) fp32.
//
// R3b: fp16 LDS tile + v_dot2_f32_f16 + single barrier. (R3 compile fix:
// cvt_pkrtz returns __fp16 vec2, fdot2 wants _Float16 vec2 -> bit_cast.)
// R2 was concurrency-bound (3 blocks/CU, 12 waves). fp16 storage halves the
// tile (48 B/px: 16 halves + 8 pad; 16B-aligned so a vector is 2x
// ds_read_b128; start bank 12L%32 covers all 32 banks once per 8 lanes ->
// conflict-free minimum) -> 28.7 KB/block -> 5 blocks/CU = 20 waves. Dots
// use v_dot2_f32_f16 (2 MAC/inst, fp32 accumulate). Norms inlined from
// registers -> the norms phase and its barrier are gone.

#define IMG_H 2048
#define IMG_W 2048
#define IMG_C 16

#define TX 32
#define TY 16
#define HX (TX + 2)      // 34
#define HY (TY + 2)      // 18
#define NPIX (HX * HY)   // 612
#define PSTRIDE 24       // halves per pixel slot (16 data + 8 pad) = 48 B

typedef _Float16 half2_t __attribute__((ext_vector_type(2)));

__device__ __forceinline__ float vdot16(const float4& x0, const float4& x1,
                                        const float4& y0, const float4& y1) {
    const half2_t* xa = (const half2_t*)&x0;
    const half2_t* xb = (const half2_t*)&x1;
    const half2_t* ya = (const half2_t*)&y0;
    const half2_t* yb = (const half2_t*)&y1;
    float acc = 0.0f;
    #pragma unroll
    for (int j = 0; j < 4; ++j) acc = __builtin_amdgcn_fdot2(xa[j], ya[j], acc, false);
    #pragma unroll
    for (int j = 0; j < 4; ++j) acc = __builtin_amdgcn_fdot2(xb[j], yb[j], acc, false);
    return acc;
}

__global__ __launch_bounds__(256, 5) void cos_sim_kernel(
    const float* __restrict__ in, float* __restrict__ out) {
    __shared__ _Float16 tile[NPIX * PSTRIDE];   // 29376 B

    const int tid = threadIdx.y * 32 + threadIdx.x;
    const int bx = blockIdx.x * TX;
    const int by = blockIdx.y * TY;

    // ---- Stage (HY x HX) halo tile into LDS as fp16 ----
    // linear i -> pixel p = i>>2, chunk k = i&3 (one float4 = 4 floats ->
    // 2 packed half2 = 8 B). Global side is lane-contiguous 16 B.
    for (int i = tid; i < NPIX * 4; i += 256) {
        const int p = i >> 2;
        const int k = i & 3;
        const int r = p / HX;
        const int c = p - r * HX;
        int gy = by + r - 1;
        int gx = bx + c - 1;
        gy = min(max(gy, 0), IMG_H - 1);
        gx = min(max(gx, 0), IMG_W - 1);
        const float4 v = *(const float4*)(in + ((size_t)gy * IMG_W + gx) * IMG_C + k * 4);
        half2_t h0 = __builtin_bit_cast(half2_t, __builtin_amdgcn_cvt_pkrtz(v.x, v.y));
        half2_t h1 = __builtin_bit_cast(half2_t, __builtin_amdgcn_cvt_pkrtz(v.z, v.w));
        half2_t* dst = (half2_t*)(tile + p * PSTRIDE + k * 4);
        dst[0] = h0;
        dst[1] = h1;
    }
    __syncthreads();

    // ---- Compute 2 output pixels per thread (single barrier kernel) ----
    #pragma unroll
    for (int rr = 0; rr < 2; ++rr) {
        const int r = threadIdx.y + rr * 8;    // tile row 0..15
        const int c = threadIdx.x;             // tile col 0..31
        const int gy = by + r;
        const int gx = bx + c;
        const int p = (r + 1) * HX + (c + 1);

        const _Float16* t = tile + p * PSTRIDE;
        const float4 a0 = *(const float4*)(t);       // 8 halves
        const float4 a1 = *(const float4*)(t + 8);   // 8 halves
        const float na = vdot16(a0, a1, a0, a1);

        float sim = 0.0f;
        #pragma unroll
        for (int q = 0; q < 4; ++q) {
            const int dy = (q & 2) ? 1 : -1;
            const int dx = (q & 1) ? 1 : -1;
            const int np = p + dy * HX + dx;
            const _Float16* u = tile + np * PSTRIDE;
            const float4 b0 = *(const float4*)(u);
            const float4 b1 = *(const float4*)(u + 8);
            const float dot = vdot16(a0, a1, b0, b1);
            const float nb  = vdot16(b0, b1, b0, b1);
            const bool valid = ((unsigned)(gy + dy) < IMG_H) && ((unsigned)(gx + dx) < IMG_W);
            const float contrib = dot * rsqrtf(fmaxf(na * nb, 1e-16f));
            sim += valid ? contrib : 0.0f;
        }
        out[(size_t)gy * IMG_W + gx] = sim;
    }
}

extern "C" void kernel_launch(void* const* d_in, const int* in_sizes, int n_in,
                              void* d_out, int out_size, void* d_ws, size_t ws_size,
                              hipStream_t stream) {
    const float* in = (const float*)d_in[0];
    float* out = (float*)d_out;
    dim3 block(32, 8, 1);
    dim3 grid(IMG_W / TX, IMG_H / TY, 1);
    cos_sim_kernel<<<grid, block, 0, stream>>>(in, out);
}